// Round 1
// baseline (2157.877 us; speedup 1.0000x reference)
//
#include <hip/hip_runtime.h>
#include <hip/hip_bf16.h>
#include <hip/hip_fp16.h>
#include <stdint.h>

#define BB 2048
#define LL 2048
#define CV 128
#define DD 1024
#define NC 1000
#define EE 6
#define HH 2048

typedef __bf16 bf16_t;
typedef _Float16 f16_t;
typedef __attribute__((ext_vector_type(8))) __bf16 bf16x8;
typedef __attribute__((ext_vector_type(8))) _Float16 f16x8;
typedef __attribute__((ext_vector_type(4))) float f32x4;

// ---------------- prep: split conv2_w into bf16 hi/lo, layout [k][co][ci] ----
__global__ void k_prep_w2(const float* __restrict__ w2,
                          bf16_t* __restrict__ hi, bf16_t* __restrict__ lo)
{
    int idx = blockIdx.x * 256 + threadIdx.x;
    if (idx >= 5 * 128 * 128) return;
    int ci = idx & 127;
    int t  = idx >> 7;
    int co = t & 127;
    int k  = t >> 7;
    float v = w2[(co * 128 + ci) * 5 + k];
    bf16_t h = (bf16_t)v;
    hi[idx] = h;
    lo[idx] = (bf16_t)(v - (float)h);
}

// ---------------- fused conv1(fp32) + conv2(bf16x3 MFMA) + relu + mean -------
__launch_bounds__(256, 2)
__global__ void k_conv(const float* __restrict__ x,  const float* __restrict__ w1,
                       const float* __restrict__ b1, const bf16_t* __restrict__ w2hi,
                       const bf16_t* __restrict__ w2lo, const float* __restrict__ b2,
                       float* __restrict__ hbar)
{
    __shared__ float  xs[266];
    __shared__ float  w1s[640];
    __shared__ float  b1s[128];
    __shared__ float  b2s[128];
    __shared__ bf16_t h1hi[131 * 136];
    __shared__ bf16_t h1lo[131 * 136];
    __shared__ float  red[4][128];

    const int tid  = threadIdx.x;
    const int b    = blockIdx.x;
    const int lane = tid & 63;
    const int wid  = tid >> 6;
    const int co0  = (wid >> 1) * 64;
    const int tw0  = (wid & 1) * 32;
    const int l15  = lane & 15;
    const int lg   = lane >> 4;

    for (int i = tid; i < 640; i += 256) w1s[i] = w1[i];
    if (tid < 128) { b1s[tid] = b1[tid]; b2s[tid] = b2[tid]; }

    float racc[4][4];
#pragma unroll
    for (int m = 0; m < 4; ++m)
#pragma unroll
        for (int r = 0; r < 4; ++r) racc[m][r] = 0.f;

    for (int c = 0; c < 8; ++c) {
        const int t2base = c * 64;
        const int t1base = 2 * t2base - 2;
        const int xbase  = 2 * t1base - 2;
        __syncthreads();
        // stage x window
        for (int j = tid; j < 265; j += 256) {
            int tx = xbase + j;
            xs[j] = (tx >= 0 && tx < LL) ? x[(size_t)b * LL + tx] : 0.f;
        }
        __syncthreads();
        // conv1 (fp32) -> relu -> split hi/lo into LDS, layout [t1row][ci]
        for (int idx = tid; idx < 131 * 128; idx += 256) {
            int row = idx >> 7, ci = idx & 127;
            int t1 = t1base + row;
            float v = 0.f;
            if (t1 >= 0 && t1 < 1024) {
                v = b1s[ci];
#pragma unroll
                for (int k = 0; k < 5; ++k) v += w1s[ci * 5 + k] * xs[2 * row + k];
                v = fmaxf(v, 0.f);
            }
            bf16_t hv = (bf16_t)v;
            h1hi[row * 136 + ci] = hv;
            h1lo[row * 136 + ci] = (bf16_t)(v - (float)hv);
        }
        __syncthreads();

        f32x4 acc[4][2];
#pragma unroll
        for (int m = 0; m < 4; ++m)
#pragma unroll
            for (int n = 0; n < 2; ++n)
#pragma unroll
                for (int r = 0; r < 4; ++r) acc[m][n][r] = 0.f;

        for (int k = 0; k < 5; ++k) {
#pragma unroll
            for (int cb = 0; cb < 4; ++cb) {
                const int ci0 = cb * 32;
                bf16x8 ah[4], al[4];
#pragma unroll
                for (int m = 0; m < 4; ++m) {
                    int co = co0 + m * 16 + l15;
                    size_t off = (size_t)((k * 128 + co) * 128 + ci0 + lg * 8);
                    ah[m] = *reinterpret_cast<const bf16x8*>(w2hi + off);
                    al[m] = *reinterpret_cast<const bf16x8*>(w2lo + off);
                }
                bf16x8 bh[2], bl[2];
#pragma unroll
                for (int n = 0; n < 2; ++n) {
                    int row = 2 * (tw0 + n * 16 + l15) + k;
                    int o = row * 136 + ci0 + lg * 8;
                    bh[n] = *reinterpret_cast<const bf16x8*>(h1hi + o);
                    bl[n] = *reinterpret_cast<const bf16x8*>(h1lo + o);
                }
#pragma unroll
                for (int m = 0; m < 4; ++m)
#pragma unroll
                    for (int n = 0; n < 2; ++n) {
                        acc[m][n] = __builtin_amdgcn_mfma_f32_16x16x32_bf16(ah[m], bh[n], acc[m][n], 0, 0, 0);
                        acc[m][n] = __builtin_amdgcn_mfma_f32_16x16x32_bf16(ah[m], bl[n], acc[m][n], 0, 0, 0);
                        acc[m][n] = __builtin_amdgcn_mfma_f32_16x16x32_bf16(al[m], bh[n], acc[m][n], 0, 0, 0);
                    }
            }
        }
        // relu(z + b2), accumulate column(=t2) partial sums
#pragma unroll
        for (int m = 0; m < 4; ++m)
#pragma unroll
            for (int r = 0; r < 4; ++r) {
                int co = co0 + m * 16 + lg * 4 + r;
                float bias = b2s[co];
                racc[m][r] += fmaxf(acc[m][0][r] + bias, 0.f) + fmaxf(acc[m][1][r] + bias, 0.f);
            }
    }
    // reduce across the 16 columns held by lanes (l&15)
#pragma unroll
    for (int m = 0; m < 4; ++m)
#pragma unroll
        for (int r = 0; r < 4; ++r) {
            float v = racc[m][r];
            v += __shfl_xor(v, 1);
            v += __shfl_xor(v, 2);
            v += __shfl_xor(v, 4);
            v += __shfl_xor(v, 8);
            racc[m][r] = v;
        }
    if (l15 == 0) {
#pragma unroll
        for (int m = 0; m < 4; ++m)
#pragma unroll
            for (int r = 0; r < 4; ++r)
                red[wid][co0 + m * 16 + lg * 4 + r] = racc[m][r];
    }
    __syncthreads();
    if (tid < 128) {
        float s = (tid < 64) ? (red[0][tid] + red[1][tid]) : (red[2][tid] + red[3][tid]);
        hbar[(size_t)b * 128 + tid] = s * (1.f / 512.f);
    }
}

// ---------------- proj: h = hbar @ proj_w^T + proj_b (pure fp32) -------------
__launch_bounds__(256)
__global__ void k_proj(const float* __restrict__ hbar, const float* __restrict__ pw,
                       const float* __restrict__ pb, float* __restrict__ h)
{
    __shared__ float hbs[64 * 128];
    const int tid = threadIdx.x;
    const int b0 = blockIdx.x * 64, d0 = blockIdx.y * 64;
    for (int i = tid * 4; i < 64 * 128; i += 1024)
        *reinterpret_cast<float4*>(&hbs[i]) =
            *reinterpret_cast<const float4*>(&hbar[(size_t)b0 * 128 + i]);
    __syncthreads();
    const int tx = tid & 15, ty = tid >> 4;
    float acc[4][4];
#pragma unroll
    for (int i = 0; i < 4; ++i)
#pragma unroll
        for (int j = 0; j < 4; ++j) acc[i][j] = 0.f;
    const float* pwr[4];
#pragma unroll
    for (int j = 0; j < 4; ++j) pwr[j] = pw + (size_t)(d0 + tx * 4 + j) * 128;
    for (int k = 0; k < 128; k += 4) {
        float4 wv[4], av[4];
#pragma unroll
        for (int j = 0; j < 4; ++j) wv[j] = *reinterpret_cast<const float4*>(pwr[j] + k);
#pragma unroll
        for (int i = 0; i < 4; ++i) av[i] = *reinterpret_cast<const float4*>(&hbs[(ty * 4 + i) * 128 + k]);
#pragma unroll
        for (int i = 0; i < 4; ++i)
#pragma unroll
            for (int j = 0; j < 4; ++j)
                acc[i][j] += av[i].x * wv[j].x + av[i].y * wv[j].y +
                             av[i].z * wv[j].z + av[i].w * wv[j].w;
    }
#pragma unroll
    for (int i = 0; i < 4; ++i) {
        int bb = b0 + ty * 4 + i;
#pragma unroll
        for (int j = 0; j < 4; ++j) {
            int d = d0 + tx * 4 + j;
            h[(size_t)bb * DD + d] = acc[i][j] + pb[d];
        }
    }
}

// ---------------- router: logits, softmax, top-2 -> combine[b][8] ------------
__launch_bounds__(256)
__global__ void k_router(const float* __restrict__ h, const float* __restrict__ rw,
                         const float* __restrict__ rb, float* __restrict__ comb)
{
    const int lane = threadIdx.x & 63;
    const int b = blockIdx.x * 4 + (threadIdx.x >> 6);
    float part[6] = {0.f, 0.f, 0.f, 0.f, 0.f, 0.f};
    for (int j = 0; j < 16; ++j) {
        int d = j * 64 + lane;
        float hv = h[(size_t)b * DD + d];
#pragma unroll
        for (int e = 0; e < 6; ++e) part[e] += rw[e * DD + d] * hv;
    }
#pragma unroll
    for (int e = 0; e < 6; ++e) {
        float v = part[e];
        for (int off = 32; off > 0; off >>= 1) v += __shfl_xor(v, off);
        part[e] = v;
    }
    if (lane == 0) {
        float lgt[6];
#pragma unroll
        for (int e = 0; e < 6; ++e) lgt[e] = part[e] + rb[e];
        int i1 = 0;
#pragma unroll
        for (int e = 1; e < 6; ++e) if (lgt[e] > lgt[i1]) i1 = e;
        int i2 = -1;
#pragma unroll
        for (int e = 0; e < 6; ++e)
            if (e != i1 && (i2 < 0 || lgt[e] > lgt[i2])) i2 = e;
        float mx = lgt[i1], s = 0.f, ex[6];
#pragma unroll
        for (int e = 0; e < 6; ++e) { ex[e] = expf(lgt[e] - mx); s += ex[e]; }
        float inv = 1.f / s;
#pragma unroll
        for (int e = 0; e < 6; ++e) comb[b * 8 + e] = 0.f;
        comb[b * 8 + 6] = 0.f; comb[b * 8 + 7] = 0.f;
        comb[b * 8 + i1] = ex[i1] * inv;
        comb[b * 8 + i2] = ex[i2] * inv;
    }
}

// ---------------- generic fp16 MFMA GEMM: C = A @ B^T ------------------------
__device__ inline f16x8 cvt8(const float4 a, const float4 b)
{
    f16x8 r;
    r[0] = (f16_t)a.x; r[1] = (f16_t)a.y; r[2] = (f16_t)a.z; r[3] = (f16_t)a.w;
    r[4] = (f16_t)b.x; r[5] = (f16_t)b.y; r[6] = (f16_t)b.z; r[7] = (f16_t)b.w;
    return r;
}

template<bool F16SRC, int ROWS>
__device__ inline void stage_tile(const void* __restrict__ src, f16_t* __restrict__ dst,
                                  int rowG0, int K, int k0, int maxRow, int tid)
{
    constexpr int PERTHR = ROWS * 64 / 256;  // halves per thread
    constexpr int TPR = 64 / PERTHR;         // threads per row
    const int row  = tid / TPR;
    const int col0 = (tid % TPR) * PERTHR;
    const bool ok = (rowG0 + row) < maxRow;
    f16_t* d = dst + row * 72 + col0;
    if constexpr (F16SRC) {
        const uint4* s = reinterpret_cast<const uint4*>(
            (const f16_t*)src + (size_t)(rowG0 + row) * K + k0 + col0);
#pragma unroll
        for (int j = 0; j < PERTHR / 8; ++j) {
            uint4 v = ok ? s[j] : make_uint4(0, 0, 0, 0);
            reinterpret_cast<uint4*>(d)[j] = v;
        }
    } else {
        const float4* s = reinterpret_cast<const float4*>(
            (const float*)src + (size_t)(rowG0 + row) * K + k0 + col0);
#pragma unroll
        for (int j = 0; j < PERTHR / 8; ++j) {
            float4 a = ok ? s[2 * j]     : make_float4(0.f, 0.f, 0.f, 0.f);
            float4 c = ok ? s[2 * j + 1] : make_float4(0.f, 0.f, 0.f, 0.f);
            reinterpret_cast<f16x8*>(d)[j] = cvt8(a, c);
        }
    }
}

// EPI: 1 = hid (relu->f16 out), 2 = eo (scale by combine, accumulate moe), 3 = cls
template<int EPI, bool AF16, int NFRAG>
__launch_bounds__(256, 2)
__global__ void k_gemm(const void* __restrict__ Ap, const float* __restrict__ Bp,
                       const float* __restrict__ bias, float* __restrict__ outF,
                       f16_t* __restrict__ outH, const float* __restrict__ combine,
                       float* __restrict__ moe, int M, int N, int K, int maxNRow, int e)
{
    constexpr int BN = NFRAG * 32;
    __shared__ f16_t As[128 * 72];
    __shared__ f16_t Bs[BN * 72];
    const int tid = threadIdx.x;
    const int m0 = blockIdx.x * 128, n0 = blockIdx.y * BN;
    const int lane = tid & 63, wid = tid >> 6;
    const int l15 = lane & 15, lg = lane >> 4;
    const int wm = wid >> 1, wn = wid & 1;

    f32x4 acc[4][NFRAG];
#pragma unroll
    for (int i = 0; i < 4; ++i)
#pragma unroll
        for (int j = 0; j < NFRAG; ++j)
#pragma unroll
            for (int r = 0; r < 4; ++r) acc[i][j][r] = 0.f;

    for (int k0 = 0; k0 < K; k0 += 64) {
        __syncthreads();
        stage_tile<AF16, 128>(Ap, As, m0, K, k0, M, tid);
        stage_tile<false, BN>((const void*)Bp, Bs, n0, K, k0, maxNRow, tid);
        __syncthreads();
#pragma unroll
        for (int kk = 0; kk < 64; kk += 32) {
            f16x8 af[4], bq[NFRAG];
#pragma unroll
            for (int i = 0; i < 4; ++i)
                af[i] = *reinterpret_cast<const f16x8*>(As + (wm * 64 + i * 16 + l15) * 72 + kk + lg * 8);
#pragma unroll
            for (int j = 0; j < NFRAG; ++j)
                bq[j] = *reinterpret_cast<const f16x8*>(Bs + (wn * (BN / 2) + j * 16 + l15) * 72 + kk + lg * 8);
#pragma unroll
            for (int i = 0; i < 4; ++i)
#pragma unroll
                for (int j = 0; j < NFRAG; ++j)
                    acc[i][j] = __builtin_amdgcn_mfma_f32_16x16x32_f16(af[i], bq[j], acc[i][j], 0, 0, 0);
        }
    }
#pragma unroll
    for (int i = 0; i < 4; ++i) {
#pragma unroll
        for (int j = 0; j < NFRAG; ++j) {
#pragma unroll
            for (int r = 0; r < 4; ++r) {
                int row = m0 + wm * 64 + i * 16 + lg * 4 + r;
                int col = n0 + wn * (BN / 2) + j * 16 + l15;
                float c = acc[i][j][r];
                if (EPI == 1) {
                    float v = fmaxf(c + bias[col], 0.f);
                    outH[(size_t)row * N + col] = (f16_t)v;
                } else if (EPI == 2) {
                    float v = c + bias[col];
                    float w = combine[row * 8 + e];
                    float prev = (e == 0) ? 0.f : moe[(size_t)row * N + col];
                    moe[(size_t)row * N + col] = prev + w * v;
                } else {
                    if (col < maxNRow)
                        outF[(size_t)row * maxNRow + col] = c + bias[col];
                }
            }
        }
    }
}

// -----------------------------------------------------------------------------
extern "C" void kernel_launch(void* const* d_in, const int* in_sizes, int n_in,
                              void* d_out, int out_size, void* d_ws, size_t ws_size,
                              hipStream_t stream)
{
    const float* x   = (const float*)d_in[0];
    const float* w1  = (const float*)d_in[1];
    const float* b1  = (const float*)d_in[2];
    const float* w2  = (const float*)d_in[3];
    const float* b2  = (const float*)d_in[4];
    const float* pw  = (const float*)d_in[5];
    const float* pb  = (const float*)d_in[6];
    const float* rw  = (const float*)d_in[7];
    const float* rb  = (const float*)d_in[8];
    const float* ew1 = (const float*)d_in[9];
    const float* eb1 = (const float*)d_in[10];
    const float* ew2 = (const float*)d_in[11];
    const float* eb2 = (const float*)d_in[12];
    const float* cw  = (const float*)d_in[13];
    const float* cb  = (const float*)d_in[14];
    float* out = (float*)d_out;

    char* ws = (char*)d_ws;
    bf16_t* w2hi = (bf16_t*)(ws + 0);          //   160 KB
    bf16_t* w2lo = (bf16_t*)(ws + 163840);     //   160 KB
    float*  hbar = (float*)(ws + 327680);      //     1 MB
    float*  h    = (float*)(ws + 1376256);     //     8 MB
    float*  comb = (float*)(ws + 9764864);     //    64 KB
    f16_t*  hid  = (f16_t*)(ws + 9830400);     //     8 MB
    float*  moe  = (float*)(ws + 18219008);    //     8 MB  (total ~25.4 MB)

    k_prep_w2<<<320, 256, 0, stream>>>(w2, w2hi, w2lo);
    k_conv<<<2048, 256, 0, stream>>>(x, w1, b1, w2hi, w2lo, b2, hbar);
    k_proj<<<dim3(32, 16), 256, 0, stream>>>(hbar, pw, pb, h);
    k_router<<<512, 256, 0, stream>>>(h, rw, rb, comb);
    for (int e = 0; e < 6; ++e) {
        k_gemm<1, false, 4><<<dim3(16, 16), 256, 0, stream>>>(
            (const void*)h, ew1 + (size_t)e * HH * DD, eb1 + (size_t)e * HH,
            nullptr, hid, nullptr, nullptr, BB, HH, DD, 1 << 30, e);
        k_gemm<2, true, 2><<<dim3(16, 16), 256, 0, stream>>>(
            (const void*)hid, ew2 + (size_t)e * DD * HH, eb2 + (size_t)e * DD,
            nullptr, nullptr, comb, moe, BB, DD, HH, 1 << 30, e);
    }
    k_gemm<3, false, 4><<<dim3(16, 8), 256, 0, stream>>>(
        (const void*)moe, cw, cb, out, nullptr, nullptr, nullptr,
        BB, DD, DD, NC, 0);
}

// Round 2
// 1269.226 us; speedup vs baseline: 1.7002x; 1.7002x over previous
//
#include <hip/hip_runtime.h>
#include <hip/hip_bf16.h>
#include <hip/hip_fp16.h>
#include <stdint.h>

#define BB 2048
#define LL 2048
#define CV 128
#define DD 1024
#define NC 1000
#define EE 6
#define HH 2048

typedef __bf16 bf16_t;
typedef _Float16 f16_t;
typedef __attribute__((ext_vector_type(8))) __bf16 bf16x8;
typedef __attribute__((ext_vector_type(8))) _Float16 f16x8;
typedef __attribute__((ext_vector_type(4))) float f32x4;

__device__ __forceinline__ void gload_lds16(const void* g, void* l)
{
    __builtin_amdgcn_global_load_lds(
        (const __attribute__((address_space(1))) unsigned int*)g,
        (__attribute__((address_space(3))) unsigned int*)l, 16, 0, 0);
}

// ---- prep: split conv2_w into bf16 hi/lo, pre-swizzled slices --------------
// slice t = cb*5 + kk (16KB = 8192 shorts): [split(hi,lo)][co 128][ci 32]
// within-plane short index: (co*32 + j) ^ ((co&7)<<3)
__global__ void k_prep_w2(const float* __restrict__ w2, bf16_t* __restrict__ wsw)
{
    int idx = blockIdx.x * 256 + threadIdx.x;
    if (idx >= 5 * 128 * 128) return;
    int kk = idx % 5;
    int t2 = idx / 5;
    int ci = t2 & 127;
    int co = t2 >> 7;
    float v = w2[idx];
    bf16_t h = (bf16_t)v;
    bf16_t l = (bf16_t)(v - (float)h);
    int cb = ci >> 5, j = ci & 31;
    int t  = cb * 5 + kk;
    int si = (co * 32 + j) ^ ((co & 7) << 3);
    wsw[(size_t)t * 8192 + si]        = h;
    wsw[(size_t)t * 8192 + 4096 + si] = l;
}

// ---- fused conv1(fp32,reg-w1) + conv2(bf16x3 MFMA, LDS-pipelined) + mean ---
__launch_bounds__(256, 3)
__global__ void k_conv(const float* __restrict__ x,  const float* __restrict__ w1,
                       const float* __restrict__ b1, const bf16_t* __restrict__ wsw,
                       const float* __restrict__ b2, float* __restrict__ hbar)
{
    __shared__ __align__(16) float w1s[640];
    __shared__ __align__(16) float b1s[128];
    __shared__ __align__(16) float b2s[128];
    __shared__ __align__(16) short h1s[2][136 * 32];   // [hi/lo][r 136][ci 32] swizzled
    __shared__ __align__(16) short wlds[2][2][4096];   // [buf][hi/lo][co128*ci32] swizzled

    const int tid  = threadIdx.x;
    const int b    = blockIdx.x;
    const int lane = tid & 63;
    const int wid  = tid >> 6;
    const int l15  = lane & 15, lg = lane >> 4;
    const int wm   = wid >> 1,  wn = wid & 1;      // co-half / t2-half
    const int jo   = tid & 3;                      // ci-octet in conv1
    const int rg   = tid >> 2;                     // row group in conv1

    for (int i = tid; i < 640; i += 256) w1s[i] = w1[i];
    if (tid < 128) { b1s[tid] = b1[tid]; b2s[tid] = b2[tid]; }

    // stage W slice 0 into wlds[0]
    {
        const bf16_t* src = wsw + (size_t)(wid * 4) * 512 + lane * 8;
        short* dst = ((short*)wlds) + (wid * 4) * 512;
#pragma unroll
        for (int o = 0; o < 4; ++o)
            gload_lds16(src + o * 512, dst + o * 512);
    }
    __syncthreads();

    const float* xrow = x + (size_t)b * LL;

    float racc[4][4];
#pragma unroll
    for (int m = 0; m < 4; ++m)
#pragma unroll
        for (int r = 0; r < 4; ++r) racc[m][r] = 0.f;

    for (int c = 0; c < 8; ++c) {
        const int t1base = 128 * c - 2;

        f32x4 acc[4][2];
#pragma unroll
        for (int m = 0; m < 4; ++m)
#pragma unroll
            for (int n = 0; n < 2; ++n)
#pragma unroll
                for (int r = 0; r < 4; ++r) acc[m][n][r] = 0.f;

        for (int cb = 0; cb < 4; ++cb) {
            // ---- conv1 for this cb's 32-ci slice: 8 ci per thread, b128 writes
            const int ci0 = cb * 32 + jo * 8;
            float wf[40], br8[8];
#pragma unroll
            for (int q = 0; q < 10; ++q)
                *reinterpret_cast<float4*>(&wf[q * 4]) =
                    *reinterpret_cast<const float4*>(&w1s[ci0 * 5 + q * 4]);
            *reinterpret_cast<float4*>(&br8[0]) = *reinterpret_cast<const float4*>(&b1s[ci0]);
            *reinterpret_cast<float4*>(&br8[4]) = *reinterpret_cast<const float4*>(&b1s[ci0 + 4]);

#pragma unroll
            for (int it = 0; it < 3; ++it) {
                int r = rg + it * 64;
                if (r < 136) {
                    int t1 = t1base + r;
                    bool valid = (unsigned)t1 < 1024u;
                    float xv[5];
#pragma unroll
                    for (int kk = 0; kk < 5; ++kk) {
                        int xg = 2 * t1 - 2 + kk;
                        xv[kk] = (valid && (unsigned)xg < 2048u) ? xrow[xg] : 0.f;
                    }
                    bf16x8 hv, lv;
#pragma unroll
                    for (int u = 0; u < 8; ++u) {
                        float v = 0.f;
                        if (valid) {
                            v = br8[u];
#pragma unroll
                            for (int kk = 0; kk < 5; ++kk) v += wf[u * 5 + kk] * xv[kk];
                            v = fmaxf(v, 0.f);
                        }
                        bf16_t h = (bf16_t)v;
                        hv[u] = h;
                        lv[u] = (bf16_t)(v - (float)h);
                    }
                    int si = (r * 32 + jo * 8) ^ (((r >> 1) & 7) << 3);
                    *reinterpret_cast<bf16x8*>(&h1s[0][si]) = hv;
                    *reinterpret_cast<bf16x8*>(&h1s[1][si]) = lv;
                }
            }
            __syncthreads();

            // ---- 5 K-steps (K=32 each), W slice double-buffered w/ prefetch
            for (int k = 0; k < 5; ++k) {
                const int t  = cb * 5 + k;
                const int tn = (t + 1) % 20;
                {
                    const bf16_t* src = wsw + (size_t)tn * 8192 + (wid * 4) * 512 + lane * 8;
                    short* dst = ((short*)wlds) + (tn & 1) * 8192 + (wid * 4) * 512;
#pragma unroll
                    for (int o = 0; o < 4; ++o)
                        gload_lds16(src + o * 512, dst + o * 512);
                }
                const short* wp = ((short*)wlds) + (t & 1) * 8192;
                bf16x8 ah[4], al[4];
#pragma unroll
                for (int m = 0; m < 4; ++m) {
                    int co_l = wm * 64 + m * 16 + l15;
                    int si = (co_l * 32 + lg * 8) ^ ((l15 & 7) << 3);
                    ah[m] = *reinterpret_cast<const bf16x8*>(wp + si);
                    al[m] = *reinterpret_cast<const bf16x8*>(wp + 4096 + si);
                }
                bf16x8 bh[2], bl[2];
#pragma unroll
                for (int n = 0; n < 2; ++n) {
                    int r = 2 * (wn * 32 + n * 16 + l15) + k;
                    int si = (r * 32 + lg * 8) ^ (((r >> 1) & 7) << 3);
                    bh[n] = *reinterpret_cast<const bf16x8*>(&h1s[0][si]);
                    bl[n] = *reinterpret_cast<const bf16x8*>(&h1s[1][si]);
                }
#pragma unroll
                for (int m = 0; m < 4; ++m)
#pragma unroll
                    for (int n = 0; n < 2; ++n) {
                        acc[m][n] = __builtin_amdgcn_mfma_f32_16x16x32_bf16(ah[m], bh[n], acc[m][n], 0, 0, 0);
                        acc[m][n] = __builtin_amdgcn_mfma_f32_16x16x32_bf16(ah[m], bl[n], acc[m][n], 0, 0, 0);
                        acc[m][n] = __builtin_amdgcn_mfma_f32_16x16x32_bf16(al[m], bh[n], acc[m][n], 0, 0, 0);
                    }
                __syncthreads();
            }
        }
        // chunk epilogue: relu(z+b2) and accumulate t2 partial sums
#pragma unroll
        for (int m = 0; m < 4; ++m)
#pragma unroll
            for (int r = 0; r < 4; ++r) {
                int co = wm * 64 + m * 16 + lg * 4 + r;
                float bias = b2s[co];
                racc[m][r] += fmaxf(acc[m][0][r] + bias, 0.f) + fmaxf(acc[m][1][r] + bias, 0.f);
            }
    }

    // reduce 16 t2-columns held across l15 lanes
#pragma unroll
    for (int m = 0; m < 4; ++m)
#pragma unroll
        for (int r = 0; r < 4; ++r) {
            float v = racc[m][r];
            v += __shfl_xor(v, 1);
            v += __shfl_xor(v, 2);
            v += __shfl_xor(v, 4);
            v += __shfl_xor(v, 8);
            racc[m][r] = v;
        }
    float* red = (float*)wlds;   // wlds dead now (vmcnt drained by last barrier)
    if (l15 == 0) {
#pragma unroll
        for (int m = 0; m < 4; ++m)
#pragma unroll
            for (int r = 0; r < 4; ++r)
                red[wid * 64 + m * 16 + lg * 4 + r] = racc[m][r];
    }
    __syncthreads();
    if (tid < 128) {
        int wm2 = tid >> 6, loc = tid & 63;
        float s = red[(wm2 * 2 + 0) * 64 + loc] + red[(wm2 * 2 + 1) * 64 + loc];
        hbar[(size_t)b * 128 + tid] = s * (1.f / 512.f);
    }
}

// ---------------- proj: h = hbar @ proj_w^T + proj_b (pure fp32) -------------
__launch_bounds__(256)
__global__ void k_proj(const float* __restrict__ hbar, const float* __restrict__ pw,
                       const float* __restrict__ pb, float* __restrict__ h)
{
    __shared__ float hbs[64 * 128];
    const int tid = threadIdx.x;
    const int b0 = blockIdx.x * 64, d0 = blockIdx.y * 64;
    for (int i = tid * 4; i < 64 * 128; i += 1024)
        *reinterpret_cast<float4*>(&hbs[i]) =
            *reinterpret_cast<const float4*>(&hbar[(size_t)b0 * 128 + i]);
    __syncthreads();
    const int tx = tid & 15, ty = tid >> 4;
    float acc[4][4];
#pragma unroll
    for (int i = 0; i < 4; ++i)
#pragma unroll
        for (int j = 0; j < 4; ++j) acc[i][j] = 0.f;
    const float* pwr[4];
#pragma unroll
    for (int j = 0; j < 4; ++j) pwr[j] = pw + (size_t)(d0 + tx * 4 + j) * 128;
    for (int k = 0; k < 128; k += 4) {
        float4 wv[4], av[4];
#pragma unroll
        for (int j = 0; j < 4; ++j) wv[j] = *reinterpret_cast<const float4*>(pwr[j] + k);
#pragma unroll
        for (int i = 0; i < 4; ++i) av[i] = *reinterpret_cast<const float4*>(&hbs[(ty * 4 + i) * 128 + k]);
#pragma unroll
        for (int i = 0; i < 4; ++i)
#pragma unroll
            for (int j = 0; j < 4; ++j)
                acc[i][j] += av[i].x * wv[j].x + av[i].y * wv[j].y +
                             av[i].z * wv[j].z + av[i].w * wv[j].w;
    }
#pragma unroll
    for (int i = 0; i < 4; ++i) {
        int bb = b0 + ty * 4 + i;
#pragma unroll
        for (int j = 0; j < 4; ++j) {
            int d = d0 + tx * 4 + j;
            h[(size_t)bb * DD + d] = acc[i][j] + pb[d];
        }
    }
}

// ---------------- router: logits, softmax, top-2 -> combine[b][8] ------------
__launch_bounds__(256)
__global__ void k_router(const float* __restrict__ h, const float* __restrict__ rw,
                         const float* __restrict__ rb, float* __restrict__ comb)
{
    const int lane = threadIdx.x & 63;
    const int b = blockIdx.x * 4 + (threadIdx.x >> 6);
    float part[6] = {0.f, 0.f, 0.f, 0.f, 0.f, 0.f};
    for (int j = 0; j < 16; ++j) {
        int d = j * 64 + lane;
        float hv = h[(size_t)b * DD + d];
#pragma unroll
        for (int e = 0; e < 6; ++e) part[e] += rw[e * DD + d] * hv;
    }
#pragma unroll
    for (int e = 0; e < 6; ++e) {
        float v = part[e];
        for (int off = 32; off > 0; off >>= 1) v += __shfl_xor(v, off);
        part[e] = v;
    }
    if (lane == 0) {
        float lgt[6];
#pragma unroll
        for (int e = 0; e < 6; ++e) lgt[e] = part[e] + rb[e];
        int i1 = 0;
#pragma unroll
        for (int e = 1; e < 6; ++e) if (lgt[e] > lgt[i1]) i1 = e;
        int i2 = -1;
#pragma unroll
        for (int e = 0; e < 6; ++e)
            if (e != i1 && (i2 < 0 || lgt[e] > lgt[i2])) i2 = e;
        float mx = lgt[i1], s = 0.f, ex[6];
#pragma unroll
        for (int e = 0; e < 6; ++e) { ex[e] = expf(lgt[e] - mx); s += ex[e]; }
        float inv = 1.f / s;
#pragma unroll
        for (int e = 0; e < 6; ++e) comb[b * 8 + e] = 0.f;
        comb[b * 8 + 6] = 0.f; comb[b * 8 + 7] = 0.f;
        comb[b * 8 + i1] = ex[i1] * inv;
        comb[b * 8 + i2] = ex[i2] * inv;
    }
}

// ---------------- generic fp16 MFMA GEMM: C = A @ B^T ------------------------
__device__ inline f16x8 cvt8(const float4 a, const float4 b)
{
    f16x8 r;
    r[0] = (f16_t)a.x; r[1] = (f16_t)a.y; r[2] = (f16_t)a.z; r[3] = (f16_t)a.w;
    r[4] = (f16_t)b.x; r[5] = (f16_t)b.y; r[6] = (f16_t)b.z; r[7] = (f16_t)b.w;
    return r;
}

template<bool F16SRC, int ROWS>
__device__ inline void stage_tile(const void* __restrict__ src, f16_t* __restrict__ dst,
                                  int rowG0, int K, int k0, int maxRow, int tid)
{
    constexpr int PERTHR = ROWS * 64 / 256;
    constexpr int TPR = 64 / PERTHR;
    const int row  = tid / TPR;
    const int col0 = (tid % TPR) * PERTHR;
    const bool ok = (rowG0 + row) < maxRow;
    f16_t* d = dst + row * 72 + col0;
    if constexpr (F16SRC) {
        const uint4* s = reinterpret_cast<const uint4*>(
            (const f16_t*)src + (size_t)(rowG0 + row) * K + k0 + col0);
#pragma unroll
        for (int j = 0; j < PERTHR / 8; ++j) {
            uint4 v = ok ? s[j] : make_uint4(0, 0, 0, 0);
            reinterpret_cast<uint4*>(d)[j] = v;
        }
    } else {
        const float4* s = reinterpret_cast<const float4*>(
            (const float*)src + (size_t)(rowG0 + row) * K + k0 + col0);
#pragma unroll
        for (int j = 0; j < PERTHR / 8; ++j) {
            float4 a = ok ? s[2 * j]     : make_float4(0.f, 0.f, 0.f, 0.f);
            float4 c = ok ? s[2 * j + 1] : make_float4(0.f, 0.f, 0.f, 0.f);
            reinterpret_cast<f16x8*>(d)[j] = cvt8(a, c);
        }
    }
}

// EPI: 1 = hid (relu->f16 out), 2 = eo (scale by combine, accumulate moe), 3 = cls
template<int EPI, bool AF16, int NFRAG>
__launch_bounds__(256, 2)
__global__ void k_gemm(const void* __restrict__ Ap, const float* __restrict__ Bp,
                       const float* __restrict__ bias, float* __restrict__ outF,
                       f16_t* __restrict__ outH, const float* __restrict__ combine,
                       float* __restrict__ moe, int M, int N, int K, int maxNRow, int e)
{
    constexpr int BN = NFRAG * 32;
    __shared__ f16_t As[128 * 72];
    __shared__ f16_t Bs[BN * 72];
    const int tid = threadIdx.x;
    const int m0 = blockIdx.x * 128, n0 = blockIdx.y * BN;
    const int lane = tid & 63, wid = tid >> 6;
    const int l15 = lane & 15, lg = lane >> 4;
    const int wm = wid >> 1, wn = wid & 1;

    f32x4 acc[4][NFRAG];
#pragma unroll
    for (int i = 0; i < 4; ++i)
#pragma unroll
        for (int j = 0; j < NFRAG; ++j)
#pragma unroll
            for (int r = 0; r < 4; ++r) acc[i][j][r] = 0.f;

    for (int k0 = 0; k0 < K; k0 += 64) {
        __syncthreads();
        stage_tile<AF16, 128>(Ap, As, m0, K, k0, M, tid);
        stage_tile<false, BN>((const void*)Bp, Bs, n0, K, k0, maxNRow, tid);
        __syncthreads();
#pragma unroll
        for (int kk = 0; kk < 64; kk += 32) {
            f16x8 af[4], bq[NFRAG];
#pragma unroll
            for (int i = 0; i < 4; ++i)
                af[i] = *reinterpret_cast<const f16x8*>(As + (wm * 64 + i * 16 + l15) * 72 + kk + lg * 8);
#pragma unroll
            for (int j = 0; j < NFRAG; ++j)
                bq[j] = *reinterpret_cast<const f16x8*>(Bs + (wn * (BN / 2) + j * 16 + l15) * 72 + kk + lg * 8);
#pragma unroll
            for (int i = 0; i < 4; ++i)
#pragma unroll
                for (int j = 0; j < NFRAG; ++j)
                    acc[i][j] = __builtin_amdgcn_mfma_f32_16x16x32_f16(af[i], bq[j], acc[i][j], 0, 0, 0);
        }
    }
#pragma unroll
    for (int i = 0; i < 4; ++i) {
#pragma unroll
        for (int j = 0; j < NFRAG; ++j) {
#pragma unroll
            for (int r = 0; r < 4; ++r) {
                int row = m0 + wm * 64 + i * 16 + lg * 4 + r;
                int col = n0 + wn * (BN / 2) + j * 16 + l15;
                float c = acc[i][j][r];
                if (EPI == 1) {
                    float v = fmaxf(c + bias[col], 0.f);
                    outH[(size_t)row * N + col] = (f16_t)v;
                } else if (EPI == 2) {
                    float v = c + bias[col];
                    float w = combine[row * 8 + e];
                    float prev = (e == 0) ? 0.f : moe[(size_t)row * N + col];
                    moe[(size_t)row * N + col] = prev + w * v;
                } else {
                    if (col < maxNRow)
                        outF[(size_t)row * maxNRow + col] = c + bias[col];
                }
            }
        }
    }
}

// -----------------------------------------------------------------------------
extern "C" void kernel_launch(void* const* d_in, const int* in_sizes, int n_in,
                              void* d_out, int out_size, void* d_ws, size_t ws_size,
                              hipStream_t stream)
{
    const float* x   = (const float*)d_in[0];
    const float* w1  = (const float*)d_in[1];
    const float* b1  = (const float*)d_in[2];
    const float* w2  = (const float*)d_in[3];
    const float* b2  = (const float*)d_in[4];
    const float* pw  = (const float*)d_in[5];
    const float* pb  = (const float*)d_in[6];
    const float* rw  = (const float*)d_in[7];
    const float* rb  = (const float*)d_in[8];
    const float* ew1 = (const float*)d_in[9];
    const float* eb1 = (const float*)d_in[10];
    const float* ew2 = (const float*)d_in[11];
    const float* eb2 = (const float*)d_in[12];
    const float* cw  = (const float*)d_in[13];
    const float* cb  = (const float*)d_in[14];
    float* out = (float*)d_out;

    char* ws = (char*)d_ws;
    bf16_t* wsw  = (bf16_t*)(ws + 0);          //   320 KB (20 slices x 16KB)
    float*  hbar = (float*)(ws + 327680);      //     1 MB
    float*  h    = (float*)(ws + 1376256);     //     8 MB
    float*  comb = (float*)(ws + 9764864);     //    64 KB
    f16_t*  hid  = (f16_t*)(ws + 9830400);     //     8 MB
    float*  moe  = (float*)(ws + 18219008);    //     8 MB

    k_prep_w2<<<320, 256, 0, stream>>>(w2, wsw);
    k_conv<<<2048, 256, 0, stream>>>(x, w1, b1, wsw, b2, hbar);
    k_proj<<<dim3(32, 16), 256, 0, stream>>>(hbar, pw, pb, h);
    k_router<<<512, 256, 0, stream>>>(h, rw, rb, comb);
    for (int e = 0; e < 6; ++e) {
        k_gemm<1, false, 4><<<dim3(16, 16), 256, 0, stream>>>(
            (const void*)h, ew1 + (size_t)e * HH * DD, eb1 + (size_t)e * HH,
            nullptr, hid, nullptr, nullptr, BB, HH, DD, 1 << 30, e);
        k_gemm<2, true, 2><<<dim3(16, 16), 256, 0, stream>>>(
            (const void*)hid, ew2 + (size_t)e * DD * HH, eb2 + (size_t)e * DD,
            nullptr, nullptr, comb, moe, BB, DD, HH, 1 << 30, e);
    }
    k_gemm<3, false, 4><<<dim3(16, 8), 256, 0, stream>>>(
        (const void*)moe, cw, cb, out, nullptr, nullptr, nullptr,
        BB, DD, DD, NC, 0);
}